// Round 9
// baseline (105.456 us; speedup 1.0000x reference)
//
#include <hip/hip_runtime.h>

// Reference: out[b,h,w,i] = in[b, h + i/8, w + i%8, 0]
//   in : (8, 512, 512, 1) f32   (8.4 MB)
//   out: (8, 505, 505, 64) f32  (522 MB -> write-BW bound)
//
// Ladder: R2 grid-stride + 4-scalar-load + NT store = 97.4 us (champion)
//         R4 grid-stride + plain                    = 143.7 us (read/write L2 thrash)
//         R6 row-block + LDS + plain                = 104.2 us (write scatter)
//         R7 32px-tile + LDS + plain, 2-iter phases = 114.0 us (barrier-starved stores)
//         R8 4KB wave bursts + NT                   = 97.8 us (burst length neutral)
// R9: dense window + plain stores + DEEP pipelining:
//   128-pixel tiles (8 store iters between barriers), double-buffered LDS
//   (stage tile j+1 overlaps stores of tile j), ONE barrier per tile.
//   Reproduces fill-kernel conditions (6.9 TB/s plain-store stream) with
//   reads off the global path.

#define BATCH   8
#define W_IN    512
#define HW_OUT  505
#define SEGS    4
#define SEGPIX  128                       // pixels per full segment (last = 121)
#define TILES   (BATCH * HW_OUT * SEGS)   // 16160
#define SW      136                       // staged floats per input row (128+7, pad)
#define SMSZ    (8 * SW)                  // 1088 floats per buffer

typedef float f32x4 __attribute__((ext_vector_type(4)));

__global__ __launch_bounds__(256) void unfold_dbuf_kernel(
    const float* __restrict__ in, float* __restrict__ out)
{
    __shared__ float sm[2][SMSZ];         // 8.7 KB total

    f32x4* __restrict__ out4 = reinterpret_cast<f32x4*>(out);

    auto stage = [&](int t, float* dst) {
        int bh  = t >> 2;
        int seg = t & 3;
        int b   = bh / HW_OUT;
        int h   = bh - b * HW_OUT;
        const float* __restrict__ rb = in + (b * W_IN + h) * W_IN + (seg << 7);
        int maxj = W_IN - (seg << 7);     // 128 for seg 3, else >= 136
        for (int s = threadIdx.x; s < SMSZ; s += 256) {
            int r = s / SW;
            int j = s - r * SW;
            dst[s] = (j < maxj) ? rb[(r << 9) + j] : 0.0f;
        }
    };

    auto store_tile = [&](int t, const float* smb) {
        int bh  = t >> 2;
        int seg = t & 3;
        int n4  = ((seg == 3) ? (HW_OUT - 3 * SEGPIX) : SEGPIX) << 4;  // 1936/2048
        f32x4* __restrict__ o = out4 + (size_t)bh * (HW_OUT * 16) + (seg << 11);
        for (int q = threadIdx.x; q < n4; q += 256) {
            int i4 = q & 15;              // float4 within 64-ch pixel
            int p  = q >> 4;              // pixel within tile
            int r  = i4 >> 1;             // window row 0..7
            int c  = (i4 & 1) << 2;       // window col base {0,4}
            const float* __restrict__ s = smb + r * SW + p + c;
            f32x4 v;
            v.x = s[0];
            v.y = s[1];
            v.z = s[2];
            v.w = s[3];
            o[q] = v;                     // PLAIN store, 8 iters deep per tile
        }
    };

    int tile = blockIdx.x;
    if (tile >= TILES) return;
    stage(tile, sm[0]);
    int cur = 0;
    for (;;) {
        int next = tile + gridDim.x;
        __syncthreads();                  // staged data ready / prev stores done
        if (next < TILES) stage(next, sm[cur ^ 1]);
        store_tile(tile, sm[cur]);
        if (next >= TILES) break;
        tile = next;
        cur ^= 1;
    }
}

extern "C" void kernel_launch(void* const* d_in, const int* in_sizes, int n_in,
                              void* d_out, int out_size, void* d_ws, size_t ws_size,
                              hipStream_t stream)
{
    const float* in  = (const float*)d_in[0];   // (8,512,512,1) f32
    float*       out = (float*)d_out;           // (8,505,505,64) f32

    const int grid = 2048;                      // ~8 tiles per block, dense window
    unfold_dbuf_kernel<<<grid, 256, 0, stream>>>(in, out);
}

// Round 10
// 105.181 us; speedup vs baseline: 1.0026x; 1.0026x over previous
//
#include <hip/hip_runtime.h>

// Reference: out[b,h,w,i] = in[b, h + i/8, w + i%8, 0]
//   in : (8, 512, 512, 1) f32   (8.4 MB)
//   out: (8, 505, 505, 64) f32  (522 MB -> write-BW bound)
//
// Ladder: R2 grid-stride + 4-scalar-load + NT store = 97.4 us (champion)
//         R4 grid-stride + plain (direct reads)     = 143.7 us
//         R5 row-block + NT (direct reads)          = 107.6 us
//         R6 row-block + LDS + plain                = 104.2 us
//         R7 32px-tile + LDS + plain (shallow)      = 114.0 us
//         R8 4KB wave bursts + NT                   = 97.8 us (burst shape neutral)
//         R9 dense + LDS dbuf + plain (deep)        = 105.5 us (plain ledger closed)
// R10: R9 structure, plain -> NT. Last untested cell: NT with a READ-FREE
// store phase (R2/R8 interleave 4 loads per NT store; loads may steal TA
// issue slots from the NT write stream). Single-variable vs R9.

#define BATCH   8
#define W_IN    512
#define HW_OUT  505
#define SEGS    4
#define SEGPIX  128                       // pixels per full segment (last = 121)
#define TILES   (BATCH * HW_OUT * SEGS)   // 16160
#define SW      136                       // staged floats per input row (128+7, pad)
#define SMSZ    (8 * SW)                  // 1088 floats per buffer

typedef float f32x4 __attribute__((ext_vector_type(4)));

__global__ __launch_bounds__(256) void unfold_dbuf_nt_kernel(
    const float* __restrict__ in, float* __restrict__ out)
{
    __shared__ float sm[2][SMSZ];         // 8.7 KB total

    f32x4* __restrict__ out4 = reinterpret_cast<f32x4*>(out);

    auto stage = [&](int t, float* dst) {
        int bh  = t >> 2;
        int seg = t & 3;
        int b   = bh / HW_OUT;
        int h   = bh - b * HW_OUT;
        const float* __restrict__ rb = in + (b * W_IN + h) * W_IN + (seg << 7);
        int maxj = W_IN - (seg << 7);     // 128 for seg 3, else >= 136
        for (int s = threadIdx.x; s < SMSZ; s += 256) {
            int r = s / SW;
            int j = s - r * SW;
            dst[s] = (j < maxj) ? rb[(r << 9) + j] : 0.0f;
        }
    };

    auto store_tile = [&](int t, const float* smb) {
        int bh  = t >> 2;
        int seg = t & 3;
        int n4  = ((seg == 3) ? (HW_OUT - 3 * SEGPIX) : SEGPIX) << 4;  // 1936/2048
        f32x4* __restrict__ o = out4 + (size_t)bh * (HW_OUT * 16) + (seg << 11);
        for (int q = threadIdx.x; q < n4; q += 256) {
            int i4 = q & 15;              // float4 within 64-ch pixel
            int p  = q >> 4;              // pixel within tile
            int r  = i4 >> 1;             // window row 0..7
            int c  = (i4 & 1) << 2;       // window col base {0,4}
            const float* __restrict__ s = smb + r * SW + p + c;
            f32x4 v;
            v.x = s[0];
            v.y = s[1];
            v.z = s[2];
            v.w = s[3];
            __builtin_nontemporal_store(v, o + q);   // NT, read-free phase
        }
    };

    int tile = blockIdx.x;
    if (tile >= TILES) return;
    stage(tile, sm[0]);
    int cur = 0;
    for (;;) {
        int next = tile + gridDim.x;
        __syncthreads();                  // staged data ready / prev stores done
        if (next < TILES) stage(next, sm[cur ^ 1]);
        store_tile(tile, sm[cur]);
        if (next >= TILES) break;
        tile = next;
        cur ^= 1;
    }
}

extern "C" void kernel_launch(void* const* d_in, const int* in_sizes, int n_in,
                              void* d_out, int out_size, void* d_ws, size_t ws_size,
                              hipStream_t stream)
{
    const float* in  = (const float*)d_in[0];   // (8,512,512,1) f32
    float*       out = (float*)d_out;           // (8,505,505,64) f32

    const int grid = 2048;                      // ~8 tiles per block, dense window
    unfold_dbuf_nt_kernel<<<grid, 256, 0, stream>>>(in, out);
}